// Round 3
// baseline (428.660 us; speedup 1.0000x reference)
//
#include <hip/hip_runtime.h>
#include <math.h>

#define BLOCK 1024
#define NWAVES (BLOCK / 64)     // 16 waves
#define NV 8                    // float4 per thread: 1024*8*4 = 32768 >= d
#define SROW_F (BLOCK * NV * 4) // 32768 floats = 128 KB LDS row stage
#define CAND_CAP 6144           // 24 KB candidate buffer
#define NREG 12                 // wave0 register-resident candidates: 64*12 = 768

// Raw barrier: drains LDS ops only, NOT vmcnt -- global_load_lds prefetches
// stay in flight across it (the m97 barrier-drain lesson; __syncthreads would
// emit s_waitcnt vmcnt(0) and serialize the pipeline).
#define BAR()      asm volatile("s_waitcnt lgkmcnt(0)\n\ts_barrier" ::: "memory")
#define WAIT_VM0() asm volatile("s_waitcnt vmcnt(0)" ::: "memory")
#define WAIT_LGKM0() asm volatile("s_waitcnt lgkmcnt(0)" ::: "memory")

__device__ __forceinline__ void gload_lds16(const float* g, float* l) {
    // 16B direct global->LDS; LDS dest must be WAVE-UNIFORM (HW adds lane*16).
    __builtin_amdgcn_global_load_lds(
        (const __attribute__((address_space(1))) void*)g,
        (__attribute__((address_space(3))) void*)l,
        16, 0, 0);
}

__device__ __forceinline__ float waveReduceMax(float v) {
#pragma unroll
    for (int off = 32; off > 0; off >>= 1)
        v = fmaxf(v, __shfl_down(v, off, 64));
    return v;
}
__device__ __forceinline__ float waveReduceSum(float v) {
#pragma unroll
    for (int off = 32; off > 0; off >>= 1)
        v += __shfl_down(v, off, 64);
    return v;
}

// Persistent blocks: grid = min(n,256) (1 block/CU), each block streams its
// rows with a software pipeline:
//   iter i: [wait my wave's prefetched slice: vmcnt(0)] -> LDS row -> regs
//           (ds_read_b128) -> lgkmcnt(0) -> ISSUE global_load_lds prefetch of
//           row i+1 into the same (wave-private) LDS slice -> max / compact /
//           solve run while the prefetch streams.
// Slice privacy makes this race-free without barriers around staging: wave w's
// gload_lds writes exactly the bytes only wave w ds_reads, and both are
// ordered by that wave's own lgkmcnt/vmcnt. Block barriers (3/iter, s_red x2 +
// compact) are raw lgkm-only. HBM stays fed through the entire compute phase:
// per-CU steady state = max(load 5.2us, compute ~3us) = load-bound, ~full duty
// vs the 67% duty of the non-pipelined version.
// Solve (verified exact, absmax=0 across R1/R2): candidates x >= rowmax-2
// (u=(x-max)/2 >= -1 >= tau*) ballot-compacted to LDS; wave0: 18 bisection
// steps on f(tau)=sum max(u-tau,0)^2 (monotone, bracket [-1,0]) then exact
// closed-form tau* = mean - sqrt((1-ss)/k) on the identified support --
// identical to the reference's sorted-cumsum formula.
__global__ __launch_bounds__(BLOCK, 4) void tsallis15_kernel(
    const float* __restrict__ x, const int* __restrict__ tgt,
    float* __restrict__ out, int n, int d, float inv_n)
{
    __shared__ __align__(16) float s_row[SROW_F];   // 131072 B
    __shared__ float s_cand[CAND_CAP];              // 24576 B
    __shared__ float s_red[NWAVES];
    __shared__ int   s_cnt;
    __shared__ float s_bcast;

    const int t     = threadIdx.x;
    const int lane  = t & 63;
    const int wave  = t >> 6;
    const int grid  = gridDim.x;
    const int row0  = blockIdx.x;
    const int d4    = d >> 2;
    const int tail0 = d4 << 2;

    if (t == 0) s_cnt = 0;

    // ---- prologue: stage row0 into LDS (wave-uniform LDS base + lane*16) ----
    {
        const float* xr = x + (size_t)row0 * (size_t)d;
#pragma unroll
        for (int j = 0; j < NV; ++j) {
            int idx = t + j * BLOCK;                    // float4 index
            int fo  = (wave << 8) + (j << 12);          // wave-uniform float offset
            if (idx < d4)
                gload_lds16(xr + fo + (lane << 2), &s_row[fo]);
        }
    }

    // ---- prologue: per-lane target-logit prefetch (wave0 only) ----
    // xt for this block's i-th row lives in wave0 lane i; fetched via __shfl at
    // use so the solve issues no late vmcnt-draining global load.
    float xt_pre = 0.0f;
    if (wave == 0) {
        int r = row0 + lane * grid;
        if (r < n) {
            int ti = tgt[r];
            xt_pre = x[(size_t)r * (size_t)d + ti];
        }
    }

    int iter = 0;
    for (int row = row0; row < n; row += grid, ++iter) {
        const float* xr = x + (size_t)row * (size_t)d;
        const int nextrow = row + grid;

        WAIT_VM0();   // my wave's staged slice of row `row` is now in LDS

        // scalar tail (d%4!=0 only): issue BEFORE prefetch so its waitcnt
        // doesn't drain the prefetch queue (vmcnt waits oldest-first).
        float tailv = -INFINITY;
        if (tail0 + t < d) tailv = xr[tail0 + t];

        // ---- LDS -> registers (frees the LDS stage for the next row) ----
        float4 r[NV];
#pragma unroll
        for (int j = 0; j < NV; ++j) {
            int idx = t + j * BLOCK;
            r[j] = (idx < d4)
                 ? *reinterpret_cast<const float4*>(&s_row[4 * idx])
                 : make_float4(-INFINITY, -INFINITY, -INFINITY, -INFINITY);
        }
        WAIT_LGKM0();  // my wave's ds_reads done before its slice is overwritten

        // ---- issue prefetch of next row into the same wave-private slice ----
        if (nextrow < n) {
            const float* xn = x + (size_t)nextrow * (size_t)d;
#pragma unroll
            for (int j = 0; j < NV; ++j) {
                int idx = t + j * BLOCK;
                int fo  = (wave << 8) + (j << 12);
                if (idx < d4)
                    gload_lds16(xn + fo + (lane << 2), &s_row[fo]);
            }
        }

        // ---- block max ----
        float m = tailv;
#pragma unroll
        for (int j = 0; j < NV; ++j)
            m = fmaxf(m, fmaxf(fmaxf(r[j].x, r[j].y), fmaxf(r[j].z, r[j].w)));
        m = waveReduceMax(m);
        if (lane == 0) s_red[wave] = m;
        BAR();
        if (wave == 0) {
            float v = (lane < NWAVES) ? s_red[lane] : -INFINITY;
            v = waveReduceMax(v);
            if (lane == 0) s_bcast = v;
        }
        BAR();
        const float rowmax = s_bcast;
        const float thr = rowmax - 2.0f;

        // ---- candidate filter via per-wave ballot compaction ----
#pragma unroll
        for (int j = 0; j < NV; ++j) {
            float4 v = r[j];
            float mx4 = fmaxf(fmaxf(v.x, v.y), fmaxf(v.z, v.w));
            unsigned long long any = __ballot(mx4 >= thr);
            if (any) {                                   // wave-uniform branch
                float vals[4] = { v.x, v.y, v.z, v.w };
#pragma unroll
                for (int c = 0; c < 4; ++c) {
                    float vv = vals[c];
                    bool pred = (vv >= thr);
                    unsigned long long mask = __ballot(pred);
                    if (mask) {
                        int base;
                        if (lane == 0) base = atomicAdd(&s_cnt, __popcll(mask));
                        base = __shfl(base, 0, 64);
                        if (pred) {
                            int pos = base + (int)__popcll(mask & ((1ull << lane) - 1ull));
                            if (pos < CAND_CAP) s_cand[pos] = (vv - rowmax) * 0.5f;
                        }
                    }
                }
            }
        }
        {   // scalar tail (0-trip when d%4==0)
            bool pred = (tailv >= thr);
            unsigned long long mask = __ballot(pred);
            if (mask) {
                int base;
                if (lane == 0) base = atomicAdd(&s_cnt, __popcll(mask));
                base = __shfl(base, 0, 64);
                if (pred) {
                    int pos = base + (int)__popcll(mask & ((1ull << lane) - 1ull));
                    if (pos < CAND_CAP) s_cand[pos] = (tailv - rowmax) * 0.5f;
                }
            }
        }
        BAR();

        // ---- wave 0: register-resident root-find + loss terms ----
        // Other waves fall through to the next iteration; its two max-phase
        // BARs require wave0, so s_cand/s_cnt can't be touched again until
        // this solve has finished. s_cnt is reset here (after reading k); the
        // write drains at wave0's next BAR before any wave reaches compact.
        if (wave == 0) {
            const int k = min(s_cnt, CAND_CAP);
            if (lane == 0) s_cnt = 0;

            float ur[NREG];
#pragma unroll
            for (int j = 0; j < NREG; ++j) {
                int idx = lane + 64 * j;
                ur[j] = (idx < k) ? s_cand[idx] : -1e30f;   // sentinel: never in support
            }

            // bisection: f monotone decreasing, f(-1)>=1>=f(0), tau* in [-1,0]
            float lo = -1.0f, hi = 0.0f;
            for (int it = 0; it < 18; ++it) {
                float tau = 0.5f * (lo + hi);
                float acc = 0.0f;
#pragma unroll
                for (int j = 0; j < NREG; ++j) {
                    float u = ur[j] - tau;
                    acc += (u > 0.0f) ? u * u : 0.0f;
                }
                for (int j = 64 * NREG + lane; j < k; j += 64) {  // overflow tail (normally 0-trip)
                    float u = s_cand[j] - tau;
                    if (u > 0.0f) acc += u * u;
                }
                float tot = waveReduceSum(acc);
                tot = __shfl(tot, 0, 64);
                if (tot >= 1.0f) lo = tau; else hi = tau;
            }
            const float tau_b = 0.5f * (lo + hi);

            // exact closed form on identified support: tau* = mean - sqrt((1-ss)/k)
            float s1 = 0.0f, s2 = 0.0f, sc = 0.0f;
#pragma unroll
            for (int j = 0; j < NREG; ++j) {
                float u = ur[j];
                if (u > tau_b) { s1 += u; s2 += u * u; sc += 1.0f; }
            }
            for (int j = 64 * NREG + lane; j < k; j += 64) {
                float u = s_cand[j];
                if (u > tau_b) { s1 += u; s2 += u * u; sc += 1.0f; }
            }
            s1 = waveReduceSum(s1); s1 = __shfl(s1, 0, 64);
            s2 = waveReduceSum(s2); s2 = __shfl(s2, 0, 64);
            sc = waveReduceSum(sc); sc = __shfl(sc, 0, 64);
            float mean  = s1 / sc;
            float ss    = s2 - s1 * mean;              // sum of squared deviations
            float delta = (1.0f - ss) / sc;
            if (delta < 0.0f) delta = 0.0f;
            const float tau_star = mean - sqrtf(delta);

            // loss terms: sum p^{3/2} = sum u^3;  dot(p, x) with x = 2u + rowmax
            float p32 = 0.0f, dot = 0.0f;
#pragma unroll
            for (int j = 0; j < NREG; ++j) {
                float u = ur[j] - tau_star;
                if (u > 0.0f) {
                    float p = u * u;
                    p32 += p * u;
                    dot += p * (2.0f * ur[j] + rowmax);
                }
            }
            for (int j = 64 * NREG + lane; j < k; j += 64) {
                float uc = s_cand[j];
                float u  = uc - tau_star;
                if (u > 0.0f) {
                    float p = u * u;
                    p32 += p * u;
                    dot += p * (2.0f * uc + rowmax);
                }
            }
            p32 = waveReduceSum(p32);
            dot = waveReduceSum(dot);

            float xt;
            if (iter < 64) {
                xt = __shfl(xt_pre, iter, 64);          // prefetched at prologue
            } else {                                     // >16K rows fallback
                xt = (lane == 0) ? xr[tgt[row]] : 0.0f;
            }
            if (lane == 0) {
                float loss = (1.0f - p32) * (4.0f / 3.0f) + dot - xt;
                atomicAdd(out, loss * inv_n);
            }
        }
    }
}

extern "C" void kernel_launch(void* const* d_in, const int* in_sizes, int n_in,
                              void* d_out, int out_size, void* d_ws, size_t ws_size,
                              hipStream_t stream) {
    const float* x   = (const float*)d_in[0];
    const int*   tgt = (const int*)d_in[1];
    float*       out = (float*)d_out;

    const int n = in_sizes[1];
    const int d = in_sizes[0] / n;

    hipMemsetAsync(out, 0, (size_t)out_size * sizeof(float), stream);
    const int grid = (n < 256) ? n : 256;
    tsallis15_kernel<<<grid, BLOCK, 0, stream>>>(x, tgt, out, n, d, 1.0f / (float)n);
}

// Round 4
// 372.276 us; speedup vs baseline: 1.1515x; 1.1515x over previous
//
#include <hip/hip_runtime.h>
#include <math.h>

#define BLOCK 1024
#define NWAVES (BLOCK / 64)   // 16 waves
#define NV 8                  // float4 per thread: 1024*8*4 = 32768 >= d
#define CAND_CAP 6144         // LDS candidate buffer (24 KB)
#define NREG 12               // wave0 register-resident candidates: 64*12 = 768

__device__ __forceinline__ float waveReduceMax(float v) {
#pragma unroll
    for (int off = 32; off > 0; off >>= 1)
        v = fmaxf(v, __shfl_down(v, off, 64));
    return v;
}
__device__ __forceinline__ float waveReduceSum(float v) {
#pragma unroll
    for (int off = 32; off > 0; off >>= 1)
        v += __shfl_down(v, off, 64);
    return v;
}

// One block per row; single HBM pass, row cached in registers (8 x float4 /
// thread @ 1024 threads covers d <= 32768).
// launch_bounds(1024, 8): this kernel compiles to ~52 VGPR (R3 measured 52 for
// a superset of this code), so the 64-VGPR budget holds WITHOUT spill and we
// get 2 blocks/CU resident (32 waves/CU, full occupancy) vs the anchor's 1.
// Rationale (R0-R3 ladder): anchor at 1 block/CU = 67% HBM duty (load 5.2us,
// then ~2.5us compact+solve with HBM idle) = 4.2 TB/s = ~60us kernel. A
// second resident block covers the compute gap; worst-case lockstep duty 81%.
// R2 failed this with NV=16 (64 payload VGPRs -> pressure); NV=8 (32 regs)
// fits. R3's global_load_lds persistent pipeline regressed 3x (181us) -- raw
// streaming + registers remains the best measured structure.
// Solve (verified exact, absmax=0 in R0-R3): candidates x >= rowmax-2
// (u=(x-max)/2 >= -1 >= tau*) ballot-compacted to LDS; wave 0 runs 18
// bisection steps on f(tau)=sum max(u-tau,0)^2 (monotone, bracket [-1,0]),
// then the exact closed form tau* = mean - sqrt((1-ss)/k) on the identified
// support -- identical to the reference's sorted-cumsum formula.
__global__ __launch_bounds__(BLOCK, 8) void tsallis15_kernel(
    const float* __restrict__ x, const int* __restrict__ tgt,
    float* __restrict__ out, int n, int d, float inv_n)
{
    __shared__ float s_cand[CAND_CAP];
    __shared__ float s_red[NWAVES];
    __shared__ int   s_cnt;
    __shared__ float s_bcast;

    const int row  = blockIdx.x;
    const int t    = threadIdx.x;
    const int lane = t & 63;
    const int wave = t >> 6;
    const float* __restrict__ xr = x + (size_t)row * (size_t)d;

    if (t == 0) s_cnt = 0;

    // ---- hoisted target-logit chain: issued first, consumed last ----
    // (two dependent global loads; latency hides under the whole row pass)
    float xt = 0.0f;
    if (t == 0) xt = xr[tgt[row]];

    // ---- single HBM pass: row -> registers ----
    float4 r[NV];
#pragma unroll
    for (int i = 0; i < NV; ++i) {
        int e = (i * BLOCK + t) * 4;
        if (e + 4 <= d) {
            r[i] = *reinterpret_cast<const float4*>(xr + e);
        } else {
            float4 v = make_float4(-INFINITY, -INFINITY, -INFINITY, -INFINITY);
            if (e < d)     v.x = xr[e];
            if (e + 1 < d) v.y = xr[e + 1];
            if (e + 2 < d) v.z = xr[e + 2];
            r[i] = v;
        }
    }

    // ---- block max ----
    float m = -INFINITY;
#pragma unroll
    for (int i = 0; i < NV; ++i)
        m = fmaxf(m, fmaxf(fmaxf(r[i].x, r[i].y), fmaxf(r[i].z, r[i].w)));
    m = waveReduceMax(m);
    if (lane == 0) s_red[wave] = m;
    __syncthreads();
    if (wave == 0) {
        float v = (lane < NWAVES) ? s_red[lane] : -INFINITY;
        v = waveReduceMax(v);
        if (lane == 0) s_bcast = v;
    }
    __syncthreads();
    const float rowmax = s_bcast;

    // ---- candidate filter via per-wave ballot compaction ----
    const float thr = rowmax - 2.0f;
#pragma unroll
    for (int i = 0; i < NV; ++i) {
        float vals[4] = { r[i].x, r[i].y, r[i].z, r[i].w };
#pragma unroll
        for (int c = 0; c < 4; ++c) {
            float v = vals[c];
            bool pred = (v >= thr);
            unsigned long long mask = __ballot(pred);
            if (mask) {                              // wave-uniform branch
                int base;
                if (lane == 0) base = atomicAdd(&s_cnt, __popcll(mask));
                base = __shfl(base, 0, 64);
                if (pred) {
                    int pos = base + (int)__popcll(mask & ((1ull << lane) - 1ull));
                    if (pos < CAND_CAP) s_cand[pos] = (v - rowmax) * 0.5f;
                }
            }
        }
    }
    __syncthreads();

    // ---- wave 0: register-resident root-find + loss terms ----
    // (r[] is dead here; the allocator reuses its registers for ur[].)
    if (wave == 0) {
        const int k = min(s_cnt, CAND_CAP);

        float ur[NREG];
#pragma unroll
        for (int j = 0; j < NREG; ++j) {
            int idx = lane + 64 * j;
            ur[j] = (idx < k) ? s_cand[idx] : -1e30f;   // sentinel: never in support
        }

        // bisection: f monotone decreasing, f(-1)>=1>=f(0), tau* in [-1,0]
        float lo = -1.0f, hi = 0.0f;
        for (int it = 0; it < 18; ++it) {
            float tau = 0.5f * (lo + hi);
            float acc = 0.0f;
#pragma unroll
            for (int j = 0; j < NREG; ++j) {
                float u = ur[j] - tau;
                acc += (u > 0.0f) ? u * u : 0.0f;
            }
            for (int j = 64 * NREG + lane; j < k; j += 64) {  // overflow tail (normally 0-trip)
                float u = s_cand[j] - tau;
                if (u > 0.0f) acc += u * u;
            }
            float tot = waveReduceSum(acc);
            tot = __shfl(tot, 0, 64);
            if (tot >= 1.0f) lo = tau; else hi = tau;
        }
        const float tau_b = 0.5f * (lo + hi);

        // exact closed form on identified support: tau* = mean - sqrt((1-ss)/k)
        float s1 = 0.0f, s2 = 0.0f, sc = 0.0f;
#pragma unroll
        for (int j = 0; j < NREG; ++j) {
            float u = ur[j];
            if (u > tau_b) { s1 += u; s2 += u * u; sc += 1.0f; }
        }
        for (int j = 64 * NREG + lane; j < k; j += 64) {
            float u = s_cand[j];
            if (u > tau_b) { s1 += u; s2 += u * u; sc += 1.0f; }
        }
        s1 = waveReduceSum(s1); s1 = __shfl(s1, 0, 64);
        s2 = waveReduceSum(s2); s2 = __shfl(s2, 0, 64);
        sc = waveReduceSum(sc); sc = __shfl(sc, 0, 64);
        float mean  = s1 / sc;
        float ss    = s2 - s1 * mean;              // sum of squared deviations
        float delta = (1.0f - ss) / sc;
        if (delta < 0.0f) delta = 0.0f;
        const float tau_star = mean - sqrtf(delta);

        // loss terms: sum p^{3/2} = sum u^3;  dot(p, x) with x = 2u + rowmax
        float p32 = 0.0f, dot = 0.0f;
#pragma unroll
        for (int j = 0; j < NREG; ++j) {
            float u = ur[j] - tau_star;
            if (u > 0.0f) {
                float p = u * u;
                p32 += p * u;
                dot += p * (2.0f * ur[j] + rowmax);
            }
        }
        for (int j = 64 * NREG + lane; j < k; j += 64) {
            float uc = s_cand[j];
            float u  = uc - tau_star;
            if (u > 0.0f) {
                float p = u * u;
                p32 += p * u;
                dot += p * (2.0f * uc + rowmax);
            }
        }
        p32 = waveReduceSum(p32);
        dot = waveReduceSum(dot);
        if (lane == 0) {
            float loss = (1.0f - p32) * (4.0f / 3.0f) + dot - xt;
            atomicAdd(out, loss * inv_n);
        }
    }
}

extern "C" void kernel_launch(void* const* d_in, const int* in_sizes, int n_in,
                              void* d_out, int out_size, void* d_ws, size_t ws_size,
                              hipStream_t stream) {
    const float* x   = (const float*)d_in[0];
    const int*   tgt = (const int*)d_in[1];
    float*       out = (float*)d_out;

    const int n = in_sizes[1];
    const int d = in_sizes[0] / n;

    hipMemsetAsync(out, 0, (size_t)out_size * sizeof(float), stream);
    tsallis15_kernel<<<n, BLOCK, 0, stream>>>(x, tgt, out, n, d, 1.0f / (float)n);
}